// Round 4
// baseline (481.800 us; speedup 1.0000x reference)
//
#include <hip/hip_runtime.h>

// Problem constants (B,C,H,W fixed by setup_inputs)
#define BB  16
#define HH  384
#define WW  1280
#define TPB 64    // one wave per block; lane l owns columns col0..col0+3
#define ROWS 8    // rows per block strip (384 = 48*8)
#define NSLOT 64  // accumulator slots, one 64B line each

__device__ __forceinline__ float4 f4add(const float4 a, const float4 b) {
    return make_float4(a.x + b.x, a.y + b.y, a.z + b.z, a.w + b.w);
}
__device__ __forceinline__ float4 f4sub(const float4 a, const float4 b) {
    return make_float4(a.x - b.x, a.y - b.y, a.z - b.z, a.w - b.w);
}
__device__ __forceinline__ float getc(const float4& v, int k) {
    return k == 0 ? v.x : k == 1 ? v.y : k == 2 ? v.z : v.w;
}

// Horizontal diff/sum for 4 columns from raw (el, q, er).
// el/er are the col-1 / col+4 values (zeroed via hl/hr at image edges).
__device__ __forceinline__ void DT(float el, const float4 q, float er,
                                   bool hl, bool hr, float4& D, float4& T) {
    float lv = hl ? el : 0.f;
    float rv = hr ? er : 0.f;
    D.x = q.y - lv;       T.x = lv + q.x + q.y;
    D.y = q.z - q.x;      T.y = q.x + q.y + q.z;
    D.z = q.w - q.y;      T.z = q.y + q.z + q.w;
    D.w = rv - q.z;       T.w = q.z + q.w + rv;
}

__global__ __launch_bounds__(TPB, 3)   // force <=~170 VGPR for 3 waves/SIMD
void NormalLoss_44478681317469_main(const float* __restrict__ pred,
                                    const float* __restrict__ gt,
                                    const float* __restrict__ mask,
                                    double* __restrict__ acc)
{
    const int lane = threadIdx.x;                    // 0..63
    const int col0 = blockIdx.x * 256 + lane * 4;    // first of 4 owned columns
    const int r0   = blockIdx.y * ROWS;
    const int b    = blockIdx.z;

    const float* pl[6];
#pragma unroll
    for (int c = 0; c < 3; ++c) {
        pl[c]     = pred + (size_t)(b * 3 + c) * HH * WW;
        pl[3 + c] = gt   + (size_t)(b * 3 + c) * HH * WW;
    }
    const float* mpl = mask + (size_t)b * HH * WW;

    const bool has_l = (col0 > 0);
    const bool has_r = (col0 + 4 < WW);
    const int  jl    = has_l ? col0 - 1 : 0;       // clamped: address always valid
    const int  jr    = has_r ? col0 + 4 : WW - 1;

    // Rolling state per plane: A = Dm1+D0, D0, Tm1, T0 (gx = A + Dp1; gy = Tp1 - Tm1)
    float4 A[6], D0[6], Tm1[6], T0[6];
    // Raw lookahead (row i+1 in flight): float4 + two edge scalars per plane.
    float4 Q[6]; float EL[6], ER[6];
    float4 mrow;

    // ---- prologue: rows r0-1 (or zero) and r0 -> state; prefetch r0+1, mask r0
    {
        const int rb0 = r0 * WW;
#pragma unroll
        for (int c = 0; c < 6; ++c) {
            float4 Dm1c = make_float4(0.f, 0.f, 0.f, 0.f);
            Tm1[c] = make_float4(0.f, 0.f, 0.f, 0.f);
            if (r0 > 0) {   // uniform per block
                const int rbm = (r0 - 1) * WW;
                float4 q = *(const float4*)(pl[c] + rbm + col0);
                float el = pl[c][rbm + jl], er = pl[c][rbm + jr];
                DT(el, q, er, has_l, has_r, Dm1c, Tm1[c]);
            }
            {
                float4 q = *(const float4*)(pl[c] + rb0 + col0);
                float el = pl[c][rb0 + jl], er = pl[c][rb0 + jr];
                DT(el, q, er, has_l, has_r, D0[c], T0[c]);
            }
            A[c] = f4add(Dm1c, D0[c]);
        }
        const int rb1 = (r0 + 1) * WW;   // r0+1 <= 377 < HH always
#pragma unroll
        for (int c = 0; c < 6; ++c) {
            Q[c]  = *(const float4*)(pl[c] + rb1 + col0);
            EL[c] = pl[c][rb1 + jl];
            ER[c] = pl[c][rb1 + jr];
        }
        mrow = *(const float4*)(mpl + rb0 + col0);
    }

    float lsum = 0.f, msum = 0.f;

#pragma unroll
    for (int k = 0; k < ROWS; ++k) {
        const int i = r0 + k;

        // Consume lookahead (loads issued one full iteration ago).
        float4 Dp1[6], Tp1[6];
#pragma unroll
        for (int c = 0; c < 6; ++c)
            DT(EL[c], Q[c], ER[c], has_l, has_r, Dp1[c], Tp1[c]);
        const float4 m = mrow;

        // Prefetch row i+2 (+ next mask row) NOW, overlapping ~380 VALU below.
        if (i + 2 < HH) {   // uniform per block
            const int rb = (i + 2) * WW;
#pragma unroll
            for (int c = 0; c < 6; ++c) {
                Q[c]  = *(const float4*)(pl[c] + rb + col0);
                EL[c] = pl[c][rb + jl];
                ER[c] = pl[c][rb + jr];
            }
        } else {
#pragma unroll
            for (int c = 0; c < 6; ++c) {
                Q[c] = make_float4(0.f, 0.f, 0.f, 0.f); EL[c] = 0.f; ER[c] = 0.f;
            }
        }
        if (k + 1 < ROWS) mrow = *(const float4*)(mpl + (i + 1) * WW + col0);

        // Gradients for 4 columns (factor 3 dropped; cancels in normalization).
        float4 gx[6], gy[6];
#pragma unroll
        for (int c = 0; c < 6; ++c) {
            gx[c] = f4add(A[c], Dp1[c]);
            gy[c] = f4sub(Tp1[c], Tm1[c]);
        }

#pragma unroll
        for (int p = 0; p < 4; ++p) {
            float gx0 = getc(gx[0], p), gx1 = getc(gx[1], p), gx2 = getc(gx[2], p);
            float gy0 = getc(gy[0], p), gy1 = getc(gy[1], p), gy2 = getc(gy[2], p);
            float hx0 = getc(gx[3], p), hx1 = getc(gx[4], p), hx2 = getc(gx[5], p);
            float hy0 = getc(gy[3], p), hy1 = getc(gy[4], p), hy2 = getc(gy[5], p);

            float n0p = gx1 * gy2 - gx2 * gy1;
            float n1p = gx2 * gy0 - gx0 * gy2;
            float n2p = gx0 * gy1 - gx1 * gy0;
            float n0g = hx1 * hy2 - hx2 * hy1;
            float n1g = hx2 * hy0 - hx0 * hy2;
            float n2g = hx0 * hy1 - hx1 * hy0;

            float sp = n0p * n0p + n1p * n1p + n2p * n2p;
            float sg = n0g * n0g + n1g * n1g + n2g * n2g;
            // ref: normal/(sqrt(s)+1e-10); rsq rel-err ~2e-6; guard s~0 -> 0
            float ip = (sp > 1e-20f) ? __builtin_amdgcn_rsqf(sp) : 0.f;
            float ig = (sg > 1e-20f) ? __builtin_amdgcn_rsqf(sg) : 0.f;

            float d0 = fabsf(n0p * ip - n0g * ig);
            float d1 = fabsf(n1p * ip - n1g * ig);
            float d2 = fabsf(n2p * ip - n2g * ig);

            float mv = getc(m, p);
            lsum += mv * (d0 + d1 + d2);
            msum += mv;
        }

        // Rotate rolling state (register renaming under full unroll).
#pragma unroll
        for (int c = 0; c < 6; ++c) {
            A[c]   = f4add(D0[c], Dp1[c]);
            D0[c]  = Dp1[c];
            Tm1[c] = T0[c];
            T0[c]  = Tp1[c];
        }
    }

    // Wave(64) reduction -> one atomic pair per block, spread over NSLOT lines.
#pragma unroll
    for (int off = 32; off > 0; off >>= 1) {
        lsum += __shfl_down(lsum, off, 64);
        msum += __shfl_down(msum, off, 64);
    }
    if (lane == 0) {
        const int linear = (blockIdx.z * gridDim.y + blockIdx.y) * gridDim.x + blockIdx.x;
        double* slot = acc + (size_t)(linear & (NSLOT - 1)) * 8;  // 64B stride
        atomicAdd(&slot[0], (double)lsum);
        atomicAdd(&slot[1], (double)msum);
    }
}

__global__ void NormalLoss_44478681317469_final(const double* __restrict__ acc,
                                                float* __restrict__ out)
{
    const int t = threadIdx.x;   // 64 threads, one per slot
    double L = acc[(size_t)t * 8 + 0];
    double M = acc[(size_t)t * 8 + 1];
#pragma unroll
    for (int off = 32; off > 0; off >>= 1) {
        L += __shfl_down(L, off, 64);
        M += __shfl_down(M, off, 64);
    }
    if (t == 0) out[0] = (float)(L / M);
}

extern "C" void kernel_launch(void* const* d_in, const int* in_sizes, int n_in,
                              void* d_out, int out_size, void* d_ws, size_t ws_size,
                              hipStream_t stream)
{
    const float* pred = (const float*)d_in[0];
    const float* gt   = (const float*)d_in[1];
    const float* mask = (const float*)d_in[2];
    double* acc = (double*)d_ws;

    // d_ws is poisoned 0xAA before every timed launch — zero the slot array.
    hipMemsetAsync(acc, 0, NSLOT * 8 * sizeof(double), stream);

    dim3 grid(WW / 256, HH / ROWS, BB);   // 5 x 48 x 16 = 3840 one-wave blocks
    NormalLoss_44478681317469_main<<<grid, dim3(TPB), 0, stream>>>(pred, gt, mask, acc);
    NormalLoss_44478681317469_final<<<1, 64, 0, stream>>>(acc, (float*)d_out);
}

// Round 5
// 284.322 us; speedup vs baseline: 1.6946x; 1.6946x over previous
//
#include <hip/hip_runtime.h>

// Problem constants (B,C,H,W fixed by setup_inputs)
#define BB  16
#define HH  384
#define WW  1280
#define TPB 128   // 2 waves; lane-thread owns 2 columns -> 256 cols per block
#define ROWS 8    // rows per block strip (384 = 48*8)
#define NSLOT 64  // accumulator slots, one 64B line each

struct F2 { float x, y; };

__device__ __forceinline__ F2 f2add(F2 a, F2 b) { return {a.x + b.x, a.y + b.y}; }

// Horizontal diff/sum for the 2 owned columns from (el, q.x, q.y, er).
// el = col0-1 value, er = col0+2 value; zeroed at image edges via hl/hr.
__device__ __forceinline__ void DT2(float el, F2 q, float er, bool hl, bool hr,
                                    F2& D, F2& T) {
    float lv = hl ? el : 0.f;
    float rv = hr ? er : 0.f;
    D.x = q.y - lv;   T.x = lv + q.x + q.y;
    D.y = rv - q.x;   T.y = q.x + q.y + rv;
}

__global__ __launch_bounds__(TPB)   // NO min-waves arg: R3 showed it forces spills
void NormalLoss_44478681317469_main(const float* __restrict__ pred,
                                    const float* __restrict__ gt,
                                    const float* __restrict__ mask,
                                    double* __restrict__ acc)
{
    const int t    = threadIdx.x;                  // 0..127
    const int col0 = blockIdx.x * 256 + t * 2;     // first of 2 owned columns
    const int r0   = blockIdx.y * ROWS;
    const int b    = blockIdx.z;

    const float* pl[6];
#pragma unroll
    for (int c = 0; c < 3; ++c) {
        pl[c]     = pred + (size_t)(b * 3 + c) * HH * WW;
        pl[3 + c] = gt   + (size_t)(b * 3 + c) * HH * WW;
    }
    const float* mpl = mask + (size_t)b * HH * WW;

    const bool has_l = (col0 > 0);
    const bool has_r = (col0 + 2 < WW);
    const int  jl    = has_l ? col0 - 1 : 0;       // clamped: address always valid
    const int  jr    = has_r ? col0 + 2 : WW - 1;

    // Rolling state per plane: A = Dm1+D0, D0, Tm1, T0
    // (gx = A + Dp1; gy = Tp1 - Tm1)  -> 4 F2 x 6 planes = 48 VGPR
    F2 A[6], D0[6], Tm1[6], T0[6];
    // Raw lookahead (row i+1 in flight): F2 + two edge scalars per plane = 24 VGPR
    F2 Q[6]; float EL[6], ER[6];
    F2 mrow;

    // ---- prologue: rows r0-1 (zero-padded) and r0 -> state; prefetch r0+1
    {
        const int rb0 = r0 * WW;
#pragma unroll
        for (int c = 0; c < 6; ++c) {
            F2 Dm1c = {0.f, 0.f};
            Tm1[c] = {0.f, 0.f};
            if (r0 > 0) {   // uniform per block
                const int rbm = (r0 - 1) * WW;
                F2 q = *(const F2*)(pl[c] + rbm + col0);
                float el = pl[c][rbm + jl], er = pl[c][rbm + jr];
                DT2(el, q, er, has_l, has_r, Dm1c, Tm1[c]);
            }
            {
                F2 q = *(const F2*)(pl[c] + rb0 + col0);
                float el = pl[c][rb0 + jl], er = pl[c][rb0 + jr];
                DT2(el, q, er, has_l, has_r, D0[c], T0[c]);
            }
            A[c] = f2add(Dm1c, D0[c]);
        }
        const int rb1 = (r0 + 1) * WW;   // r0+1 <= 377 < HH always
#pragma unroll
        for (int c = 0; c < 6; ++c) {
            Q[c]  = *(const F2*)(pl[c] + rb1 + col0);
            EL[c] = pl[c][rb1 + jl];
            ER[c] = pl[c][rb1 + jr];
        }
        mrow = *(const F2*)(mpl + rb0 + col0);
    }

    float lsum = 0.f, msum = 0.f;

#pragma unroll
    for (int k = 0; k < ROWS; ++k) {
        const int i = r0 + k;

        // Consume lookahead (loads issued one full iteration ago).
        F2 Dp1[6], Tp1[6];
#pragma unroll
        for (int c = 0; c < 6; ++c)
            DT2(EL[c], Q[c], ER[c], has_l, has_r, Dp1[c], Tp1[c]);
        const F2 m = mrow;

        // Prefetch row i+2 (+ next mask row) NOW; flight covers the math below.
        if (i + 2 < HH) {   // uniform per block
            const int rb = (i + 2) * WW;
#pragma unroll
            for (int c = 0; c < 6; ++c) {
                Q[c]  = *(const F2*)(pl[c] + rb + col0);
                EL[c] = pl[c][rb + jl];
                ER[c] = pl[c][rb + jr];
            }
        } else {
#pragma unroll
            for (int c = 0; c < 6; ++c) { Q[c] = {0.f, 0.f}; EL[c] = 0.f; ER[c] = 0.f; }
        }
        if (k + 1 < ROWS) mrow = *(const F2*)(mpl + (i + 1) * WW + col0);

        // Gradients for the 2 columns (factor 3 dropped; cancels in normalize).
        F2 gx[6], gy[6];
#pragma unroll
        for (int c = 0; c < 6; ++c) {
            gx[c] = f2add(A[c], Dp1[c]);
            gy[c].x = Tp1[c].x - Tm1[c].x;
            gy[c].y = Tp1[c].y - Tm1[c].y;
        }

#pragma unroll
        for (int p = 0; p < 2; ++p) {
            float gx0 = p ? gx[0].y : gx[0].x, gx1 = p ? gx[1].y : gx[1].x, gx2 = p ? gx[2].y : gx[2].x;
            float gy0 = p ? gy[0].y : gy[0].x, gy1 = p ? gy[1].y : gy[1].x, gy2 = p ? gy[2].y : gy[2].x;
            float hx0 = p ? gx[3].y : gx[3].x, hx1 = p ? gx[4].y : gx[4].x, hx2 = p ? gx[5].y : gx[5].x;
            float hy0 = p ? gy[3].y : gy[3].x, hy1 = p ? gy[4].y : gy[4].x, hy2 = p ? gy[5].y : gy[5].x;

            float n0p = gx1 * gy2 - gx2 * gy1;
            float n1p = gx2 * gy0 - gx0 * gy2;
            float n2p = gx0 * gy1 - gx1 * gy0;
            float n0g = hx1 * hy2 - hx2 * hy1;
            float n1g = hx2 * hy0 - hx0 * hy2;
            float n2g = hx0 * hy1 - hx1 * hy0;

            float sp = n0p * n0p + n1p * n1p + n2p * n2p;
            float sg = n0g * n0g + n1g * n1g + n2g * n2g;
            // ref: normal/(sqrt(s)+1e-10); rsq rel-err ~2e-6; guard s~0 -> 0
            float ip = (sp > 1e-20f) ? __builtin_amdgcn_rsqf(sp) : 0.f;
            float ig = (sg > 1e-20f) ? __builtin_amdgcn_rsqf(sg) : 0.f;

            float d0 = fabsf(n0p * ip - n0g * ig);
            float d1 = fabsf(n1p * ip - n1g * ig);
            float d2 = fabsf(n2p * ip - n2g * ig);

            float mv = p ? m.y : m.x;
            lsum += mv * (d0 + d1 + d2);
            msum += mv;
        }

        // Rotate rolling state (register renaming under full unroll).
#pragma unroll
        for (int c = 0; c < 6; ++c) {
            A[c]   = f2add(D0[c], Dp1[c]);
            D0[c]  = Dp1[c];
            Tm1[c] = T0[c];
            T0[c]  = Tp1[c];
        }
    }

    // Wave reduce -> cross-wave via LDS -> one atomic pair per block (spread).
#pragma unroll
    for (int off = 32; off > 0; off >>= 1) {
        lsum += __shfl_down(lsum, off, 64);
        msum += __shfl_down(msum, off, 64);
    }
    __shared__ float sL[TPB / 64], sM[TPB / 64];
    const int lane = t & 63, wid = t >> 6;
    if (lane == 0) { sL[wid] = lsum; sM[wid] = msum; }
    __syncthreads();
    if (t == 0) {
        float L = sL[0] + sL[1];
        float M = sM[0] + sM[1];
        const int linear = (blockIdx.z * gridDim.y + blockIdx.y) * gridDim.x + blockIdx.x;
        double* slot = acc + (size_t)(linear & (NSLOT - 1)) * 8;  // 64B stride
        atomicAdd(&slot[0], (double)L);
        atomicAdd(&slot[1], (double)M);
    }
}

__global__ void NormalLoss_44478681317469_final(const double* __restrict__ acc,
                                                float* __restrict__ out)
{
    const int t = threadIdx.x;   // 64 threads, one per slot
    double L = acc[(size_t)t * 8 + 0];
    double M = acc[(size_t)t * 8 + 1];
#pragma unroll
    for (int off = 32; off > 0; off >>= 1) {
        L += __shfl_down(L, off, 64);
        M += __shfl_down(M, off, 64);
    }
    if (t == 0) out[0] = (float)(L / M);
}

extern "C" void kernel_launch(void* const* d_in, const int* in_sizes, int n_in,
                              void* d_out, int out_size, void* d_ws, size_t ws_size,
                              hipStream_t stream)
{
    const float* pred = (const float*)d_in[0];
    const float* gt   = (const float*)d_in[1];
    const float* mask = (const float*)d_in[2];
    double* acc = (double*)d_ws;

    // d_ws is poisoned 0xAA before every timed launch — zero the slot array.
    hipMemsetAsync(acc, 0, NSLOT * 8 * sizeof(double), stream);

    dim3 grid(WW / 256, HH / ROWS, BB);   // 5 x 48 x 16 = 3840 blocks, 2 waves each
    NormalLoss_44478681317469_main<<<grid, dim3(TPB), 0, stream>>>(pred, gt, mask, acc);
    NormalLoss_44478681317469_final<<<1, 64, 0, stream>>>(acc, (float*)d_out);
}

// Round 6
// 235.344 us; speedup vs baseline: 2.0472x; 1.2081x over previous
//
#include <hip/hip_runtime.h>

// Problem constants (B,C,H,W fixed by setup_inputs)
#define BB  16
#define HH  384
#define WW  1280
#define TPB 256   // threads per block, along W (1280 = 5*256)
#define ROWS 32   // rows per block strip (384 = 12*32): long-lived blocks,
                  // grid 960 = 3.75 blocks/CU fully co-resident (R5 theory:
                  // R1's 3840 short blocks were launch-rate starved, occ 17%)
#define NSLOT 64  // accumulator slots, one 64B line each

// Raw 3-tap row fetch with column zero-padding.
__device__ __forceinline__ void load_row3(const float* __restrict__ plane, int i, int j,
                                          float& a, float& b, float& c) {
    const float* row = plane + (size_t)i * WW;
    a = (j > 0)      ? row[j - 1] : 0.f;
    b = row[j];
    c = (j < WW - 1) ? row[j + 1] : 0.f;
}

__global__ __launch_bounds__(TPB)   // no min-waves arg: R3 showed it forces spills
void NormalLoss_44478681317469_main(const float* __restrict__ pred,
                                    const float* __restrict__ gt,
                                    const float* __restrict__ mask,
                                    double* __restrict__ acc)
{
    const int j  = blockIdx.x * TPB + threadIdx.x;   // column
    const int r0 = blockIdx.y * ROWS;                // strip start row
    const int b  = blockIdx.z;

    const float* pl[6];
#pragma unroll
    for (int c = 0; c < 3; ++c) {
        pl[c]     = pred + (size_t)(b * 3 + c) * HH * WW;
        pl[3 + c] = gt   + (size_t)(b * 3 + c) * HH * WW;
    }
    const float* mpl = mask + (size_t)b * HH * WW;

    // Rolling D (horiz diff) / T (horiz sum) state for rows i-1, i.
    float Dm1[6], D0[6], Tm1[6], T0[6];
    // Raw lookahead: row i+1 currently in flight from memory.
    float Ra[6], Rb[6], Rc[6];

#pragma unroll
    for (int c = 0; c < 6; ++c) {
        if (r0 > 0) {   // uniform per block
            float a, bb, cc; load_row3(pl[c], r0 - 1, j, a, bb, cc);
            Dm1[c] = cc - a; Tm1[c] = a + bb + cc;
        } else { Dm1[c] = 0.f; Tm1[c] = 0.f; }   // zero padding above row 0
        {
            float a, bb, cc; load_row3(pl[c], r0, j, a, bb, cc);
            D0[c] = cc - a; T0[c] = a + bb + cc;
        }
    }

    // Issue loads for row r0+1 (consumed at top of first iteration).
#pragma unroll
    for (int c = 0; c < 6; ++c)
        load_row3(pl[c], r0 + 1, j, Ra[c], Rb[c], Rc[c]);   // r0+1 <= 353 < HH
    float mrow = mpl[(size_t)r0 * WW + j];

    float lsum = 0.f, msum = 0.f;

#pragma unroll 2    // rolling loop: keeps VGPR ~R1-level, allows rename-by-2
    for (int k = 0; k < ROWS; ++k) {
        const int i = r0 + k;

        // Consume lookahead -> D/T for row i+1 (loads issued one iter ago).
        float Dp1[6], Tp1[6];
#pragma unroll
        for (int c = 0; c < 6; ++c) {
            Dp1[c] = Rc[c] - Ra[c];
            Tp1[c] = Ra[c] + Rb[c] + Rc[c];
        }
        float m = mrow;

        // Prefetch row i+2 (+ next mask row) NOW, overlapping the math below.
        if (i + 2 < HH) {   // uniform per block
#pragma unroll
            for (int c = 0; c < 6; ++c) load_row3(pl[c], i + 2, j, Ra[c], Rb[c], Rc[c]);
        } else {
#pragma unroll
            for (int c = 0; c < 6; ++c) { Ra[c] = 0.f; Rb[c] = 0.f; Rc[c] = 0.f; }
        }
        if (k + 1 < ROWS) mrow = mpl[(size_t)(i + 1) * WW + j];

        // Gradients (global factor 3 dropped; cancels in normalization)
        float gx[6], gy[6];
#pragma unroll
        for (int c = 0; c < 6; ++c) {
            gx[c] = Dm1[c] + D0[c] + Dp1[c];
            gy[c] = Tp1[c] - Tm1[c];
        }

        // normal = cross(gx_vec, gy_vec), per reference component expressions
        float n0p = gx[1] * gy[2] - gx[2] * gy[1];
        float n1p = gx[2] * gy[0] - gx[0] * gy[2];
        float n2p = gx[0] * gy[1] - gx[1] * gy[0];
        float n0g = gx[4] * gy[5] - gx[5] * gy[4];
        float n1g = gx[5] * gy[3] - gx[3] * gy[5];
        float n2g = gx[3] * gy[4] - gx[4] * gy[3];

        float sp = n0p * n0p + n1p * n1p + n2p * n2p;
        float sg = n0g * n0g + n1g * n1g + n2g * n2g;
        // ref: normal/(sqrt(s)+1e-10); rsq rel-err ~2e-6; guard s~0 -> 0
        float ip = (sp > 1e-20f) ? __builtin_amdgcn_rsqf(sp) : 0.f;
        float ig = (sg > 1e-20f) ? __builtin_amdgcn_rsqf(sg) : 0.f;

        float d0 = fabsf(n0p * ip - n0g * ig);
        float d1 = fabsf(n1p * ip - n1g * ig);
        float d2 = fabsf(n2p * ip - n2g * ig);

        lsum += m * (d0 + d1 + d2);
        msum += m;

        // Rotate rolling state (plain copies; unroll-2 lets compiler rename).
#pragma unroll
        for (int c = 0; c < 6; ++c) {
            Dm1[c] = D0[c]; D0[c] = Dp1[c];
            Tm1[c] = T0[c]; T0[c] = Tp1[c];
        }
    }

    // Wave(64) shuffle reduction, cross-wave via LDS, one atomic pair per block.
#pragma unroll
    for (int off = 32; off > 0; off >>= 1) {
        lsum += __shfl_down(lsum, off, 64);
        msum += __shfl_down(msum, off, 64);
    }
    __shared__ float sL[TPB / 64], sM[TPB / 64];
    const int lane = threadIdx.x & 63;
    const int wid  = threadIdx.x >> 6;
    if (lane == 0) { sL[wid] = lsum; sM[wid] = msum; }
    __syncthreads();
    if (threadIdx.x == 0) {
        float L = 0.f, M = 0.f;
#pragma unroll
        for (int w = 0; w < TPB / 64; ++w) { L += sL[w]; M += sM[w]; }
        const int linear = (blockIdx.z * gridDim.y + blockIdx.y) * gridDim.x + blockIdx.x;
        double* slot = acc + (size_t)(linear & (NSLOT - 1)) * 8;  // 64B stride
        atomicAdd(&slot[0], (double)L);
        atomicAdd(&slot[1], (double)M);
    }
}

__global__ void NormalLoss_44478681317469_final(const double* __restrict__ acc,
                                                float* __restrict__ out)
{
    const int t = threadIdx.x;   // 64 threads, one per slot
    double L = acc[(size_t)t * 8 + 0];
    double M = acc[(size_t)t * 8 + 1];
#pragma unroll
    for (int off = 32; off > 0; off >>= 1) {
        L += __shfl_down(L, off, 64);
        M += __shfl_down(M, off, 64);
    }
    if (t == 0) out[0] = (float)(L / M);
}

extern "C" void kernel_launch(void* const* d_in, const int* in_sizes, int n_in,
                              void* d_out, int out_size, void* d_ws, size_t ws_size,
                              hipStream_t stream)
{
    const float* pred = (const float*)d_in[0];
    const float* gt   = (const float*)d_in[1];
    const float* mask = (const float*)d_in[2];
    double* acc = (double*)d_ws;

    // d_ws is poisoned 0xAA before every timed launch — zero the slot array.
    hipMemsetAsync(acc, 0, NSLOT * 8 * sizeof(double), stream);

    dim3 grid(WW / TPB, HH / ROWS, BB);   // 5 x 12 x 16 = 960 co-resident blocks
    NormalLoss_44478681317469_main<<<grid, dim3(TPB), 0, stream>>>(pred, gt, mask, acc);
    NormalLoss_44478681317469_final<<<1, 64, 0, stream>>>(acc, (float*)d_out);
}